// Round 9
// baseline (251.974 us; speedup 1.0000x reference)
//
#include <hip/hip_runtime.h>

// WeatherLSTM round 14: R6 structure + SKEWED phase order per wave parity.
//  - grid 256 x 512 thr (8 waves, 2/SIMD), 16 samples/block, 1 block/CU.
//  - Invariant measured R6/R10/R12/R13: step ~2500-2650cy, VALU-busy ~1250cy
//    in EVERY config -> busy half = act issue (8 wave-acts/SIMD x ~154cy,
//    trans@16cy dominant), stall half never overlaps because all waves sit
//    in the SAME phase (lockstep on barrier; R13 1 wave/SIMD had no partner).
//  - This round: identical work, identical totals, ONE barrier/step (exact
//    R6 scheme), but the loop body order is wave-parity-skewed:
//      role A: M0(k) ACT0(k) M1(k) ACT1(k)
//      role B: M1(k) ACT1(k) M0(k) ACT0(k)
//    so each SIMD's two waves are in opposite phase types at any instant
//    (m114: MFMA-wave + VALU-wave co-schedule fully). role=(w^(w>>2))&1 is
//    robust to either wave->SIMD mapping (R12-verified trick).
//  - Race analysis (per interval, 1 barrier at end): M0 reads h0 slot kbn,
//    ACT0 writes h0 slot kb; M1 reads h1 slot kb (+h0 kbn), ACT1 writes h1
//    slot kbn. All same-interval read/write pairs disjoint; all producer->
//    consumer pairs cross the barrier. Rings depth 2, zero-initialized.
//  - x-table eliminated (R12/R13-verified): quad0 lanes hold x(k) in f4
//    regs, prefetch x(k+1) each iter. LDS = h rings only, 13.3KB.
//  - Wave w owns units w*8..w*8+7 as 2 mixed-gate 16-row tiles (row perm
//    ul*4+g, per-row scale), 14 MFMA + 4 acts/thread/step: exact R6 math
//    (verified absmax 4.9e-4 since R2).
//  - Acts: weights prescaled log2e (2log2e for g); shared-rcp with fused
//    i*tanh(g) = B*D*(Eg-1)*R. 7 trans + ~21 VALU per act.
//  - FAILURE CRITERION: >=170us -> within-block desync dead; attack act
//    formula (cross-act batched rcp) next.

typedef _Float16 h8 __attribute__((ext_vector_type(8)));
typedef _Float16 h4 __attribute__((ext_vector_type(4)));
typedef float f4 __attribute__((ext_vector_type(4)));

#define ROWB 208
#define HBUF (16 * ROWB)              // 3328 B per h slot
#define H0_OFF 0                      // 2 slots
#define H1_OFF (2 * HBUF)             // 2 slots
#define SMEM_TOTAL (4 * HBUF)         // 13312 B

#define K1F 1.4426950408889634f   // log2(e)
#define K2F 2.8853900817779268f   // 2*log2(e)

__device__ __forceinline__ float exp2_(float x) {
#if __has_builtin(__builtin_amdgcn_exp2f)
  return __builtin_amdgcn_exp2f(x);
#else
  float r; asm("v_exp_f32 %0, %1" : "=v"(r) : "v"(x)); return r;
#endif
}
__device__ __forceinline__ float rcp_(float x) {
#if __has_builtin(__builtin_amdgcn_rcpf)
  return __builtin_amdgcn_rcpf(x);
#else
  float r; asm("v_rcp_f32 %0, %1" : "=v"(r) : "v"(x)); return r;
#endif
}

__device__ __forceinline__ f4 mfma16(h8 a, h8 b, f4 c) {
  return __builtin_amdgcn_mfma_f32_16x16x32_f16(a, b, c, 0, 0, 0);
}

__device__ __forceinline__ h8 load_w8s(const float* __restrict__ p, float sc) {
  h8 r;
#pragma unroll
  for (int j = 0; j < 8; j++) r[j] = (_Float16)(p[j] * sc);
  return r;
}

// a[0]=i,a[1]=f,a[3]=o prescaled K1F; a[2]=g prescaled K2F.
// sigm(i)*tanh(g) = (Eg-1)/(A*C) = B*D*(Eg-1)*R with R=1/(ABCD).
__device__ __forceinline__ void lstm_act(f4 a, float& c, float& h) {
  float Ei = exp2_(-a[0]);
  float Ef = exp2_(-a[1]);
  float Eg = exp2_(a[2]);
  float Eo = exp2_(-a[3]);
  float A = 1.f + Ei, B = 1.f + Ef, C = 1.f + Eg, D = 1.f + Eo;
  float AB = A * B, CD = C * D, BD = B * D;
  float R  = rcp_(AB * CD);
  float fv = (A * CD) * R;               // sigm(f)
  float ig = (BD * (Eg - 1.f)) * R;      // sigm(i)*tanh(g)
  float ov = (AB * C) * R;               // sigm(o)
  c = fv * c + ig;
  float r2 = rcp_(exp2_(c * K2F) + 1.f);
  h = ov * (1.f - 2.f * r2);
}

extern "C" __global__ void __launch_bounds__(512, 2)
weather_lstm_mfma14(const float* __restrict__ x,
                    const float* __restrict__ Wih0, const float* __restrict__ Whh0,
                    const float* __restrict__ bih0, const float* __restrict__ bhh0,
                    const float* __restrict__ Wih1, const float* __restrict__ Whh1,
                    const float* __restrict__ bih1, const float* __restrict__ bhh1,
                    const float* __restrict__ W1, const float* __restrict__ b1,
                    const float* __restrict__ W2, const float* __restrict__ b2,
                    float* __restrict__ out)
{
  __shared__ __align__(16) unsigned char smem[SMEM_TOTAL];
  const int tid  = threadIdx.x;
  const int lane = tid & 63;
  const int w    = tid >> 6;      // wave 0..7 -> units w*8..w*8+7
  const int col  = lane & 15;     // sample index (B-frag n / C col)
  const int quad = lane >> 4;     // 0..3
  const int sB   = blockIdx.x * 16;
  const int roleA = ((w ^ (w >> 2)) & 1) == 0;   // mapping-robust parity

  // ---- A-frag row decode: m = lane&15 = ul*4 + g; unit = w*8 + t*4 + ul ----
  const int g_  = col & 3;
  const int ul_ = col >> 2;
  const float asc = (g_ == 2) ? K2F : K1F;

  // ---- load + prescale weight A-frags (once), 2 tiles ----
  h8 a0[2][3], a1i[2][2], a1h[2][2];
#pragma unroll
  for (int t = 0; t < 2; t++) {
    const int r = g_ * 64 + w * 8 + t * 4 + ul_;
#pragma unroll
    for (int f = 0; f < 2; f++) {
      a0[t][f]  = load_w8s(Whh0 + r * 64 + f * 32 + quad * 8, asc);
      a1i[t][f] = load_w8s(Wih1 + r * 64 + f * 32 + quad * 8, asc);
      a1h[t][f] = load_w8s(Whh1 + r * 64 + f * 32 + quad * 8, asc);
    }
    h8 xw = {};
    if (quad == 0) {
#pragma unroll
      for (int j = 0; j < 4; j++) xw[j] = (_Float16)(Wih0[r * 4 + j] * asc);
    }
    a0[t][2] = xw;
  }

  // ---- biases (prescaled): unit w*8+t*4+quad, gate reg ----
  f4 bias0v[2], bias1v[2];
#pragma unroll
  for (int t = 0; t < 2; t++) {
#pragma unroll
    for (int reg = 0; reg < 4; reg++) {
      const int rr = reg * 64 + w * 8 + t * 4 + quad;
      const float bs = (reg == 2) ? K2F : K1F;
      bias0v[t][reg] = (bih0[rr] + bhh0[rr]) * bs;
      bias1v[t][reg] = (bih1[rr] + bhh1[rr]) * bs;
    }
  }

  // ---- zero h rings ----
  for (int idx = tid; idx < SMEM_TOTAL / 4; idx += 512) ((int*)smem)[idx] = 0;
  __syncthreads();

  // ---- x prefetch registers (quad0 lanes) ----
  f4 xc = {};
  if (quad == 0)
    xc = *(const f4*)(x + ((size_t)(sB + col) * 168 + 0) * 4);

  float c0[2] = {0.f, 0.f}, c1[2] = {0.f, 0.f}, hl[2] = {0.f, 0.f};
  const int bo = col * ROWB + quad * 16;                // B-frag byte offset
  const int wo = col * ROWB + (w * 8 + quad) * 2;       // h-write byte offset

  for (int k = 0; k <= 168; k++) {
    const int kb = k & 1, kbn = kb ^ 1;
    const unsigned char* h0r = smem + H0_OFF + kbn * HBUF;  // h0(k-1)
    unsigned char*       h0w = smem + H0_OFF + kb  * HBUF;  // h0(k)
    const unsigned char* h1r = smem + H1_OFF + kb  * HBUF;  // h1(k-2)
    unsigned char*       h1w = smem + H1_OFF + kbn * HBUF;  // h1(k-1)

    // x(k) fragment from regs; prefetch x(k+1)
    h8 bx = {};
    if (quad == 0) {
#pragma unroll
      for (int j = 0; j < 4; j++) bx[j] = (_Float16)xc[j];
    }
    {
      const int kn = (k < 167) ? k + 1 : 167;
      f4 xn = xc;
      if (quad == 0)
        xn = *(const f4*)(x + ((size_t)(sB + col) * 168 + kn) * 4);
      xc = xn;
    }

    f4 A[2], C[2];
    if (roleA) {
      // ---- M0(k) ----
      h8 b0  = *(const h8*)(h0r + bo);
      h8 b1v = *(const h8*)(h0r + bo + 64);
#pragma unroll
      for (int t = 0; t < 2; t++) {
        A[t] = mfma16(a0[t][0], b0, bias0v[t]);
        A[t] = mfma16(a0[t][1], b1v, A[t]);
        A[t] = mfma16(a0[t][2], bx, A[t]);
      }
      // ---- ACT0(k) ----
      if (k < 168) {
#pragma unroll
        for (int t = 0; t < 2; t++) {
          float h0o;
          lstm_act(A[t], c0[t], h0o);
          *(_Float16*)(h0w + wo + t * 8) = (_Float16)h0o;
        }
      }
      // ---- M1(k) ----
      h8 q0 = *(const h8*)(h1r + bo);
      h8 q1 = *(const h8*)(h1r + bo + 64);
#pragma unroll
      for (int t = 0; t < 2; t++) {
        C[t] = mfma16(a1i[t][0], b0, bias1v[t]);
        C[t] = mfma16(a1i[t][1], b1v, C[t]);
        C[t] = mfma16(a1h[t][0], q0, C[t]);
        C[t] = mfma16(a1h[t][1], q1, C[t]);
      }
      // ---- ACT1(k) ----
      if (k > 0) {
#pragma unroll
        for (int t = 0; t < 2; t++) {
          lstm_act(C[t], c1[t], hl[t]);
          *(_Float16*)(h1w + wo + t * 8) = (_Float16)hl[t];
        }
      }
    } else {
      // ---- M1(k) first ----
      h8 b0  = *(const h8*)(h0r + bo);
      h8 b1v = *(const h8*)(h0r + bo + 64);
      h8 q0  = *(const h8*)(h1r + bo);
      h8 q1  = *(const h8*)(h1r + bo + 64);
#pragma unroll
      for (int t = 0; t < 2; t++) {
        C[t] = mfma16(a1i[t][0], b0, bias1v[t]);
        C[t] = mfma16(a1i[t][1], b1v, C[t]);
        C[t] = mfma16(a1h[t][0], q0, C[t]);
        C[t] = mfma16(a1h[t][1], q1, C[t]);
      }
      // ---- ACT1(k) ----
      if (k > 0) {
#pragma unroll
        for (int t = 0; t < 2; t++) {
          lstm_act(C[t], c1[t], hl[t]);
          *(_Float16*)(h1w + wo + t * 8) = (_Float16)hl[t];
        }
      }
      // ---- M0(k) ----
#pragma unroll
      for (int t = 0; t < 2; t++) {
        A[t] = mfma16(a0[t][0], b0, bias0v[t]);
        A[t] = mfma16(a0[t][1], b1v, A[t]);
        A[t] = mfma16(a0[t][2], bx, A[t]);
      }
      // ---- ACT0(k) ----
      if (k < 168) {
#pragma unroll
        for (int t = 0; t < 2; t++) {
          float h0o;
          lstm_act(A[t], c0[t], h0o);
          *(_Float16*)(h0w + wo + t * 8) = (_Float16)h0o;
        }
      }
    }
    __syncthreads();
  }

  // ---------- MLP head (h rings dead; overlay) ----------
  float* fh = (float*)smem;              // [16][64] final h2, fp32
#pragma unroll
  for (int t = 0; t < 2; t++)
    fh[col * 64 + (w * 8 + t * 4 + quad)] = hl[t];
  __syncthreads();

  {
    const int u = tid & 63, grp = tid >> 6;  // 8 grps x 2 samples
    const float* w1r = W1 + u * 64;
    float* zl = (float*)(smem + 4096);       // [16][64]
#pragma unroll
    for (int rep = 0; rep < 2; rep++) {
      const int s = grp + rep * 8;
      float za = b1[u];
      const float* f0 = fh + s * 64;
      for (int j = 0; j < 64; j++) za += w1r[j] * f0[j];
      zl[s * 64 + u] = fmaxf(za, 0.f);
    }
  }
  __syncthreads();

  if (tid < 192) {
    const float* zl = (const float*)(smem + 4096);
    const int s = tid / 12, o = tid - s * 12;
    float a = b2[o];
    for (int j = 0; j < 64; j++) a += W2[o * 64 + j] * zl[s * 64 + j];
    out[(sB + s) * 12 + o] = a;
  }
}

extern "C" void kernel_launch(void* const* d_in, const int* in_sizes, int n_in,
                              void* d_out, int out_size, void* d_ws, size_t ws_size,
                              hipStream_t stream) {
  (void)in_sizes; (void)n_in; (void)d_ws; (void)ws_size; (void)out_size;
  const float* x    = (const float*)d_in[0];
  const float* Wih0 = (const float*)d_in[1];
  const float* Whh0 = (const float*)d_in[2];
  const float* bih0 = (const float*)d_in[3];
  const float* bhh0 = (const float*)d_in[4];
  const float* Wih1 = (const float*)d_in[5];
  const float* Whh1 = (const float*)d_in[6];
  const float* bih1 = (const float*)d_in[7];
  const float* bhh1 = (const float*)d_in[8];
  const float* W1   = (const float*)d_in[9];
  const float* b1   = (const float*)d_in[10];
  const float* W2   = (const float*)d_in[11];
  const float* b2   = (const float*)d_in[12];

  weather_lstm_mfma14<<<dim3(256), dim3(512), 0, stream>>>(
      x, Wih0, Whh0, bih0, bhh0, Wih1, Whh1, bih1, bhh1, W1, b1, W2, b2,
      (float*)d_out);
}

// Round 10
// 231.471 us; speedup vs baseline: 1.0886x; 1.0886x over previous
//
#include <hip/hip_runtime.h>

// WeatherLSTM round 15: EXACT R6 champion structure + 4-way batched rcp acts.
//  - Post-mortem R7-R14: FIVE structural variants (dup-col 2-block, LDS flags,
//    anti-phase groups, layer-split, skewed order) all flat-to-worse vs R6's
//    lock-step 176us. Model revision: the ~1270cy "VALU busy"/step is mostly
//    TRANS-PIPE OCCUPANCY (v_exp/v_rcp quarter-rate, 16cy/wave-inst):
//    2 waves x 28 trans x 16cy = 896cy/SIMD-step of un-overlappable hardware
//    pipe time. Scheduling can't shrink a saturated pipe; only fewer trans can.
//  - This round: ONE variable vs R6. Acts unchanged mathematically, but the
//    4 acts/thread (2 L0 + 2 L1, all live in R6's body) share reciprocals:
//      4x rcp(ABCD)   -> 1 rcp + 9 mul (prefix/suffix products)
//      4x rcp(e^2c+1) -> 1 rcp + 9 mul
//    Trans/thread-step 28 -> 22 (-21%); +18 VALU. Ranges: P<~1e4 each,
//    product <~1e18 << f32 max; rcp relerr ~1e-7 negligible vs 4.9e-4 absmax.
//  - Edge-step garbage acts (k=0 L1, k=168 L0) are computed (bounded: zero
//    rings + bias) but state commits guarded exactly as R6.
//  - Everything else BYTE-IDENTICAL to R6: grid 256x512 (8 waves, 2/SIMD),
//    2 tiles/wave, 5 ds_reads + 14 MFMAs/iter, x-table [169][16][8] LDS,
//    1 barrier/step, MLP head. MFMA layouts verified R2-R14 (absmax 4.9e-4).
//  - Decision: drop ~= trans savings -> trans-bound confirmed, cut deeper
//    next (poly tanh). Flat -> issue-floor model wrong -> latency/barrier.

typedef _Float16 h8 __attribute__((ext_vector_type(8)));
typedef _Float16 h4 __attribute__((ext_vector_type(4)));
typedef float f4 __attribute__((ext_vector_type(4)));

#define ROWB 208
#define HBUF (16 * ROWB)          // 3328 B per h buffer
#define XTAB_OFF 0
#define XTAB_BYTES (169 * 256)    // 43264 B (row 168 = zero pad)
#define H0_OFF XTAB_BYTES
#define H1_OFF (H0_OFF + 2 * HBUF)
#define SMEM_TOTAL (H1_OFF + 2 * HBUF)   // 56576 B

#define K1F 1.4426950408889634f   // log2(e)
#define K2F 2.8853900817779268f   // 2*log2(e)

__device__ __forceinline__ float exp2_(float x) {
#if __has_builtin(__builtin_amdgcn_exp2f)
  return __builtin_amdgcn_exp2f(x);
#else
  float r; asm("v_exp_f32 %0, %1" : "=v"(r) : "v"(x)); return r;
#endif
}
__device__ __forceinline__ float rcp_(float x) {
#if __has_builtin(__builtin_amdgcn_rcpf)
  return __builtin_amdgcn_rcpf(x);
#else
  float r; asm("v_rcp_f32 %0, %1" : "=v"(r) : "v"(x)); return r;
#endif
}

__device__ __forceinline__ f4 mfma16(h8 a, h8 b, f4 c) {
  return __builtin_amdgcn_mfma_f32_16x16x32_f16(a, b, c, 0, 0, 0);
}

__device__ __forceinline__ h8 load_w8s(const float* __restrict__ p, float sc) {
  h8 r;
#pragma unroll
  for (int j = 0; j < 8; j++) r[j] = (_Float16)(p[j] * sc);
  return r;
}

extern "C" __global__ void __launch_bounds__(512, 2)
weather_lstm_mfma15(const float* __restrict__ x,
                    const float* __restrict__ Wih0, const float* __restrict__ Whh0,
                    const float* __restrict__ bih0, const float* __restrict__ bhh0,
                    const float* __restrict__ Wih1, const float* __restrict__ Whh1,
                    const float* __restrict__ bih1, const float* __restrict__ bhh1,
                    const float* __restrict__ W1, const float* __restrict__ b1,
                    const float* __restrict__ W2, const float* __restrict__ b2,
                    float* __restrict__ out)
{
  __shared__ __align__(16) unsigned char smem[SMEM_TOTAL];
  const int tid  = threadIdx.x;
  const int lane = tid & 63;
  const int w    = tid >> 6;      // wave 0..7 -> units w*8..w*8+7
  const int col  = lane & 15;     // sample index (B-frag n / C col)
  const int quad = lane >> 4;     // 0..3
  const int sB   = blockIdx.x * 16;

  // ---- A-frag row decode: m = lane&15 = ul*4 + g; unit = w*8 + t*4 + ul ----
  const int g_  = col & 3;
  const int ul_ = col >> 2;
  const float asc = (g_ == 2) ? K2F : K1F;

  // ---- load + prescale weight A-frags (once), 2 tiles ----
  h8 a0[2][3], a1i[2][2], a1h[2][2];
#pragma unroll
  for (int t = 0; t < 2; t++) {
    const int r = g_ * 64 + w * 8 + t * 4 + ul_;
#pragma unroll
    for (int f = 0; f < 2; f++) {
      a0[t][f]  = load_w8s(Whh0 + r * 64 + f * 32 + quad * 8, asc);
      a1i[t][f] = load_w8s(Wih1 + r * 64 + f * 32 + quad * 8, asc);
      a1h[t][f] = load_w8s(Whh1 + r * 64 + f * 32 + quad * 8, asc);
    }
    h8 xw = {};
    if (quad == 0) {
#pragma unroll
      for (int j = 0; j < 4; j++) xw[j] = (_Float16)(Wih0[r * 4 + j] * asc);
    }
    a0[t][2] = xw;
  }

  // ---- biases (prescaled): lane C rows reg -> gate reg, unit w*8+t*4+quad ----
  f4 bias0v[2], bias1v[2];
#pragma unroll
  for (int t = 0; t < 2; t++) {
#pragma unroll
    for (int reg = 0; reg < 4; reg++) {
      const int rr = reg * 64 + w * 8 + t * 4 + quad;
      const float bs = (reg == 2) ? K2F : K1F;
      bias0v[t][reg] = (bih0[rr] + bhh0[rr]) * bs;
      bias1v[t][reg] = (bih1[rr] + bhh1[rr]) * bs;
    }
  }

  // ---- zero LDS, build x table ----
  for (int idx = tid; idx < SMEM_TOTAL / 4; idx += 512) ((int*)smem)[idx] = 0;
  __syncthreads();
  for (int idx = tid; idx < 16 * 168; idx += 512) {
    const int c_ = idx / 168, t_ = idx - c_ * 168;
    f4 xv = *(const f4*)(x + ((size_t)(sB + c_) * 168 + t_) * 4);
    h4 xh;
#pragma unroll
    for (int j = 0; j < 4; j++) xh[j] = (_Float16)xv[j];
    *(h4*)(smem + XTAB_OFF + t_ * 256 + c_ * 16) = xh;
  }
  __syncthreads();

  float c0[2] = {0.f, 0.f}, c1[2] = {0.f, 0.f}, hl[2] = {0.f, 0.f};
  const int bo  = col * ROWB + quad * 16;                // B-frag byte offset
  const int wo0 = col * ROWB + (w * 8 + quad) * 2;       // tile0 h-write offset
  const unsigned char* xp = smem + XTAB_OFF + col * 16;

  for (int k = 0; k <= 168; k++) {
    const int kb = k & 1, kbn = kb ^ 1;
    const unsigned char* h0r = smem + H0_OFF + kbn * HBUF;  // h0(k-1)
    unsigned char*       h0w = smem + H0_OFF + kb  * HBUF;  // h0(k)
    const unsigned char* h1r = smem + H1_OFF + kb  * HBUF;  // h1(k-2)
    unsigned char*       h1w = smem + H1_OFF + kbn * HBUF;  // h1(k-1)

    // ---- shared ds_reads (SAME for both tiles -> 5 reads feed 14 MFMAs) ----
    h8 b0  = *(const h8*)(h0r + bo);         // h0(k-1) k 0..31
    h8 b1v = *(const h8*)(h0r + bo + 64);    // h0(k-1) k 32..63
    h8 bx  = *(const h8*)(xp + k * 256);     // x(k) (quad0 data; others A=0)
    h8 q0  = *(const h8*)(h1r + bo);         // h1(k-2) k 0..31
    h8 q1  = *(const h8*)(h1r + bo + 64);    // h1(k-2) k 32..63

    // ---- 14 MFMAs, 4 independent chains ----
    f4 A[2], C[2];
#pragma unroll
    for (int t = 0; t < 2; t++) {
      A[t] = mfma16(a0[t][0], b0, bias0v[t]);       // L0 tile t
      C[t] = mfma16(a1i[t][0], b0, bias1v[t]);      // L1 tile t
      A[t] = mfma16(a0[t][1], b1v, A[t]);
      C[t] = mfma16(a1i[t][1], b1v, C[t]);
      A[t] = mfma16(a0[t][2], bx, A[t]);
      C[t] = mfma16(a1h[t][0], q0, C[t]);
      C[t] = mfma16(a1h[t][1], q1, C[t]);
    }

    // ---- batched activations: acts {0,1}=L0 tiles, {2,3}=L1 tiles ----
    // stage 1: gate exponentials + numerators (16 independent exp2)
    float P[4], fvn[4], ign[4], ovn[4];
#pragma unroll
    for (int a = 0; a < 4; ++a) {
      f4 g = (a < 2) ? A[a] : C[a - 2];
      float Ei = exp2_(-g[0]);
      float Ef = exp2_(-g[1]);
      float Eg = exp2_(g[2]);
      float Eo = exp2_(-g[3]);
      float Aa = 1.f + Ei, Bb = 1.f + Ef, Cc = 1.f + Eg, Dd = 1.f + Eo;
      float AB = Aa * Bb, CD = Cc * Dd, BD = Bb * Dd;
      P[a]   = AB * CD;             // < ~1e4 (gates small: weights x0.05)
      fvn[a] = Aa * CD;             // sigm(f)   = fvn * R
      ign[a] = BD * (Eg - 1.f);     // sigm(i)*tanh(g) = ign * R
      ovn[a] = AB * Cc;             // sigm(o)   = ovn * R
    }
    // 4-way shared reciprocal #1: R[a] = 1/P[a]  (1 rcp + 9 mul vs 4 rcp)
    float p01 = P[0] * P[1], p23 = P[2] * P[3];
    float rr  = rcp_(p01 * p23);
    float rA  = rr * p23, rC = rr * p01;
    float R0 = rA * P[1], R1 = rA * P[0], R2 = rC * P[3], R3 = rC * P[2];
    // stage 2: c update + tanh(c) denominators (4 independent exp2)
    float cn[4], Dden[4];
    {
      float fv0 = fvn[0] * R0, fv1 = fvn[1] * R1, fv2 = fvn[2] * R2, fv3 = fvn[3] * R3;
      cn[0] = fv0 * c0[0] + ign[0] * R0;
      cn[1] = fv1 * c0[1] + ign[1] * R1;
      cn[2] = fv2 * c1[0] + ign[2] * R2;
      cn[3] = fv3 * c1[1] + ign[3] * R3;
#pragma unroll
      for (int a = 0; a < 4; ++a) Dden[a] = exp2_(cn[a] * K2F) + 1.f;
    }
    // 4-way shared reciprocal #2: r2[a] = 1/Dden[a]
    float q01 = Dden[0] * Dden[1], q23 = Dden[2] * Dden[3];
    float sr  = rcp_(q01 * q23);
    float sA  = sr * q23, sC = sr * q01;
    float s0 = sA * Dden[1], s1 = sA * Dden[0], s2 = sC * Dden[3], s3 = sC * Dden[2];
    // h = sigm(o) * tanh(c) = (ovn*R) * (1 - 2*r2)
    float h_0 = (ovn[0] * R0) * (1.f - 2.f * s0);
    float h_1 = (ovn[1] * R1) * (1.f - 2.f * s1);
    float h_2 = (ovn[2] * R2) * (1.f - 2.f * s2);
    float h_3 = (ovn[3] * R3) * (1.f - 2.f * s3);

    // ---- guarded commits (exact R6 semantics) ----
    if (k < 168) {               // L0(k) real
      c0[0] = cn[0]; c0[1] = cn[1];
      *(_Float16*)(h0w + wo0)     = (_Float16)h_0;
      *(_Float16*)(h0w + wo0 + 8) = (_Float16)h_1;
    }
    if (k > 0) {                 // L1(k-1) real
      c1[0] = cn[2]; c1[1] = cn[3];
      hl[0] = h_2; hl[1] = h_3;
      *(_Float16*)(h1w + wo0)     = (_Float16)h_2;
      *(_Float16*)(h1w + wo0 + 8) = (_Float16)h_3;
    }
    __syncthreads();
  }

  // ---------- MLP head (x table region dead; overlay) ----------
  float* fh = (float*)smem;              // [16][64] final h2, fp32
#pragma unroll
  for (int t = 0; t < 2; t++)
    fh[col * 64 + (w * 8 + t * 4 + quad)] = hl[t];
  __syncthreads();

  {
    const int u = tid & 63, grp = tid >> 6;  // 8 grps x 2 samples
    const float* w1r = W1 + u * 64;
    float* zl = (float*)(smem + 4096);       // [16][64]
#pragma unroll
    for (int rep = 0; rep < 2; rep++) {
      const int s = grp + rep * 8;
      float za = b1[u];
      const float* f0 = fh + s * 64;
      for (int j = 0; j < 64; j++) za += w1r[j] * f0[j];
      zl[s * 64 + u] = fmaxf(za, 0.f);
    }
  }
  __syncthreads();

  if (tid < 192) {
    const float* zl = (const float*)(smem + 4096);
    const int s = tid / 12, o = tid - s * 12;
    float a = b2[o];
    for (int j = 0; j < 64; j++) a += W2[o * 64 + j] * zl[s * 64 + j];
    out[(sB + s) * 12 + o] = a;
  }
}

extern "C" void kernel_launch(void* const* d_in, const int* in_sizes, int n_in,
                              void* d_out, int out_size, void* d_ws, size_t ws_size,
                              hipStream_t stream) {
  (void)in_sizes; (void)n_in; (void)d_ws; (void)ws_size; (void)out_size;
  const float* x    = (const float*)d_in[0];
  const float* Wih0 = (const float*)d_in[1];
  const float* Whh0 = (const float*)d_in[2];
  const float* bih0 = (const float*)d_in[3];
  const float* bhh0 = (const float*)d_in[4];
  const float* Wih1 = (const float*)d_in[5];
  const float* Whh1 = (const float*)d_in[6];
  const float* bih1 = (const float*)d_in[7];
  const float* bhh1 = (const float*)d_in[8];
  const float* W1   = (const float*)d_in[9];
  const float* b1   = (const float*)d_in[10];
  const float* W2   = (const float*)d_in[11];
  const float* b2   = (const float*)d_in[12];

  weather_lstm_mfma15<<<dim3(256), dim3(512), 0, stream>>>(
      x, Wih0, Whh0, bih0, bhh0, Wih1, Whh1, bih1, bhh1, W1, b1, W2, b2,
      (float*)d_out);
}